// Round 5
// baseline (957.421 us; speedup 1.0000x reference)
//
#include <hip/hip_runtime.h>

typedef __attribute__((ext_vector_type(8))) short short8;
typedef __attribute__((ext_vector_type(4))) short short4_t;
typedef __attribute__((ext_vector_type(4))) float f32x4;
typedef __attribute__((ext_vector_type(16))) float f32x16;

#define DEVI static __device__ __forceinline__

DEVI float b2f(short s) { return __uint_as_float(((unsigned)(unsigned short)s) << 16); }
DEVI short f2bs(float x) {
  unsigned u = __float_as_uint(x);
  unsigned r = (u + 0x7FFFu + ((u >> 16) & 1u)) >> 16;
  return (short)(unsigned short)r;
}

DEVI void gload16(const short* g, short* l) {
  __builtin_amdgcn_global_load_lds(
      (const __attribute__((address_space(1))) void*)g,
      (__attribute__((address_space(3))) void*)l, 16, 0, 0);
}

DEVI void wg_barrier() {
  asm volatile("" ::: "memory");
  __builtin_amdgcn_s_barrier();
  asm volatile("" ::: "memory");
}

// Stage one 128x64 bf16 unit: 8 waves x 2 gloads x 64 lanes x 16B = 16KB.
// LDS dest linear (wave-uniform + lane*16); global source pre-swizzled:
// lane row = rowbase_w + i*8 + (l>>3); source slot = (l&7) ^ (l>>3).
// Resulting LDS: unit[row][64] with slot c holding k-chunk (c ^ (row&7)).
DEVI void stage_unit(const short* __restrict__ gTile, int K, int rowbase_w,
                     short* lUnit, int w, int l) {
  const int rr = l >> 3;
  const int slot = ((l & 7) ^ rr) << 3;
  const short* g0 = gTile + (size_t)(rowbase_w + rr) * K + slot;
  gload16(g0, lUnit + w * 1024);
  gload16(g0 + (size_t)8 * K, lUnit + w * 1024 + 512);
}

// ---------- fused LayerNorm -> bf16 for text AND audio (one launch) --------
__global__ __launch_bounds__(256) void ln2_kernel(
    const float* __restrict__ text, const float* __restrict__ audio,
    const float* __restrict__ gt, const float* __restrict__ bt,
    const float* __restrict__ ga, const float* __restrict__ ba,
    short* __restrict__ tb, short* __restrict__ ab) {
  const size_t row = (size_t)blockIdx.x * 4 + (threadIdx.x >> 6);
  const int lane = threadIdx.x & 63;
  const bool isT = row < 32768;
  const float* X = isT ? text + row * 1024 : audio + (row - 32768) * 1024;
  const float* g = isT ? gt : ga;
  const float* b = isT ? bt : ba;
  short* Y = isT ? tb + row * 1024 : ab + (row - 32768) * 1024;
  f32x4 x[4];
  float s = 0.f, ss = 0.f;
#pragma unroll
  for (int j = 0; j < 4; j++) {
    x[j] = *(const f32x4*)(X + j * 256 + lane * 4);
#pragma unroll
    for (int c = 0; c < 4; c++) { s += x[j][c]; ss += x[j][c] * x[j][c]; }
  }
  for (int o = 32; o > 0; o >>= 1) { s += __shfl_xor(s, o, 64); ss += __shfl_xor(ss, o, 64); }
  const float m = s * (1.f / 1024.f);
  const float rstd = rsqrtf(ss * (1.f / 1024.f) - m * m + 1e-5f);
#pragma unroll
  for (int j = 0; j < 4; j++) {
    f32x4 gg = *(const f32x4*)(g + j * 256 + lane * 4);
    f32x4 bb = *(const f32x4*)(b + j * 256 + lane * 4);
    short4_t o4;
#pragma unroll
    for (int c = 0; c < 4; c++) o4[c] = f2bs((x[j][c] - m) * rstd * gg[c] + bb[c]);
    *(short4_t*)(Y + j * 256 + lane * 4) = o4;
  }
}

// ------------ W [K][N] fp32 -> Wt [N][K] bf16, all three weights -----------
__global__ __launch_bounds__(256) void wtrans3_kernel(
    const float* __restrict__ W0, const float* __restrict__ W1,
    const float* __restrict__ W2, short* __restrict__ T0,
    short* __restrict__ T1, short* __restrict__ T2) {
  const float* W = blockIdx.z == 0 ? W0 : (blockIdx.z == 1 ? W1 : W2);
  short* Wt = blockIdx.z == 0 ? T0 : (blockIdx.z == 1 ? T1 : T2);
  __shared__ float tile[32][33];
  const int tx = threadIdx.x & 31;
  const int ty = threadIdx.x >> 5;  // 0..7
  const int c0 = blockIdx.x * 32, r0 = blockIdx.y * 32;
#pragma unroll
  for (int rr = 0; rr < 4; rr++)
    tile[ty + rr * 8][tx] = W[(size_t)(r0 + ty + rr * 8) * 1024 + c0 + tx];
  __syncthreads();
#pragma unroll
  for (int rr = 0; rr < 4; rr++)
    Wt[(size_t)(c0 + ty + rr * 8) * 1024 + r0 + tx] = f2bs(tile[tx][ty + rr * 8]);
}

// ============ 256x256 2-phase MFMA GEMM, 32x32x16 core =====================
// A bf16 [M][K] K-contig, B bf16 [N][K] K-contig, BK=64, 8 waves (2Mx4N),
// per-wave out 128x64 = 4 mtiles(32) x 2 ntiles(32). LDS 128KB.
// Ph0: read A-reg0/1 + B-reg0 (20 ds_reads), 16 MFMA. Ph1: B-reg1 (4), 16 MFMA.
// Uniform vmcnt(8) once per phase; 4 barriers / K-tile.
// EPI 0: +bias[col] bf16 | 1: exp(s*scale) masked + row-sum partials bf16
// EPI 3: +bias[row] bf16 | 5: *rsinv[row] bf16
template <int EPI>
__global__ __launch_bounds__(512, 2) void gemm8_kernel(
    const short* __restrict__ A, const short* __restrict__ B, void* __restrict__ Cp,
    int K, int ldc, long Abatch, long Bbatch, long Cbatch,
    const float* __restrict__ bias, const int* __restrict__ mask, float scale,
    float* __restrict__ partial, const float* __restrict__ rsinv) {
  __shared__ short lds[65536];
  const int t = threadIdx.x;
  const int w = t >> 6, l = t & 63;
  const int wm = w >> 2, wn = w & 3;
  const int l31 = l & 31, lk = l >> 5, l7 = l & 7;

  // XCD-chunked block swizzle (nwg % 8 == 0 by construction)
  const int gx = gridDim.x, gy = gridDim.y;
  const int nwg = gx * gy * (int)gridDim.z;
  int lin = blockIdx.x + gx * (blockIdx.y + gy * blockIdx.z);
  lin = (lin & 7) * (nwg >> 3) + (lin >> 3);
  const int bx = lin % gx;
  const int by = (lin / gx) % gy;
  const int bz = lin / (gx * gy);

  const int rowBase = by * 256;
  const int colBase = bx * 256;
  const short* Ab = A + (size_t)bz * Abatch + (size_t)rowBase * K;
  const short* Bb = B + (size_t)bz * Bbatch + (size_t)colBase * K;

  short* As = lds;            // [buf][reg][128][64]
  short* Bs = lds + 32768;

  f32x16 acc[4][2];
#pragma unroll
  for (int m = 0; m < 4; m++)
#pragma unroll
    for (int n = 0; n < 2; n++)
#pragma unroll
      for (int i = 0; i < 16; i++) acc[m][n][i] = 0.f;

  const int nt = K >> 6;
  const int ntm1 = nt - 1;

  // stage row bases (per wave)
  const int rbA0 = (w >> 2) * 128 + (w & 3) * 16;  // A region 0
  const int rbA1 = rbA0 + 64;                      // A region 1
  const int rbB0 = (w >> 1) * 64 + (w & 1) * 16;   // B region 0
  const int rbB1 = rbB0 + 32;                      // B region 1

  // ---- prologue: 7 units (A0,A1,B0,B1 of t0; A0,A1,B0 of t1) = 14 loads
  stage_unit(Ab, K, rbA0, As, w, l);
  stage_unit(Ab, K, rbA1, As + 8192, w, l);
  stage_unit(Bb, K, rbB0, Bs, w, l);
  stage_unit(Bb, K, rbB1, Bs + 8192, w, l);
  stage_unit(Ab + 64, K, rbA0, As + 16384, w, l);
  stage_unit(Ab + 64, K, rbA1, As + 24576, w, l);
  stage_unit(Bb + 64, K, rbB0, Bs + 16384, w, l);
  asm volatile("s_waitcnt vmcnt(8)" ::: "memory");
  wg_barrier();

  // fragment read offsets (elements)
  int sl[4];
#pragma unroll
  for (int ks = 0; ks < 4; ks++) sl[ks] = (((ks << 1) | lk) ^ l7) << 3;
  const int rA0 = (wm * 64 + l31) * 64;        // mtile 0 / 2 (region 0 / 1)
  const int rA1 = (wm * 64 + 32 + l31) * 64;   // mtile 1 / 3
  const int rB = (wn * 32 + l31) * 64;

  for (int tt = 0; tt < nt; ++tt) {
    const int c = tt & 1;
    const short* Ac = As + c * 16384;
    const short* Bc = Bs + c * 16384;
    short* Acur = As + c * 16384;
    short* Bcur = Bs + c * 16384;
    short* Bnx = Bs + (c ^ 1) * 16384;
    const int k1 = ((tt + 1 <= ntm1) ? tt + 1 : ntm1) * 64;
    const int k2 = ((tt + 2 <= ntm1) ? tt + 2 : ntm1) * 64;

    // ---- Ph0: all A + B-reg0; stage B-r1(t+1); 16 MFMA
    short8 aL0[4], aL1[4], aH0[4], aH1[4], bF[4];
#pragma unroll
    for (int ks = 0; ks < 4; ks++) {
      aL0[ks] = *(const short8*)&Ac[rA0 + sl[ks]];
      aL1[ks] = *(const short8*)&Ac[rA1 + sl[ks]];
      aH0[ks] = *(const short8*)&Ac[8192 + rA0 + sl[ks]];
      aH1[ks] = *(const short8*)&Ac[8192 + rA1 + sl[ks]];
      bF[ks] = *(const short8*)&Bc[rB + sl[ks]];
    }
    stage_unit(Bb + k1, K, rbB1, Bnx + 8192, w, l);
    wg_barrier();
    __builtin_amdgcn_s_setprio(1);
#pragma unroll
    for (int ks = 0; ks < 4; ks++) {
      acc[0][0] = __builtin_amdgcn_mfma_f32_32x32x16_bf16(aL0[ks], bF[ks], acc[0][0], 0, 0, 0);
      acc[1][0] = __builtin_amdgcn_mfma_f32_32x32x16_bf16(aL1[ks], bF[ks], acc[1][0], 0, 0, 0);
      acc[2][0] = __builtin_amdgcn_mfma_f32_32x32x16_bf16(aH0[ks], bF[ks], acc[2][0], 0, 0, 0);
      acc[3][0] = __builtin_amdgcn_mfma_f32_32x32x16_bf16(aH1[ks], bF[ks], acc[3][0], 0, 0, 0);
    }
    __builtin_amdgcn_s_setprio(0);
    asm volatile("s_waitcnt vmcnt(8)" ::: "memory");
    wg_barrier();

    // ---- Ph1: B-reg1; stage A-r0(t+2), A-r1(t+2), B-r0(t+2); 16 MFMA
    short8 bG[4];
#pragma unroll
    for (int ks = 0; ks < 4; ks++)
      bG[ks] = *(const short8*)&Bc[8192 + rB + sl[ks]];
    stage_unit(Ab + k2, K, rbA0, Acur, w, l);
    stage_unit(Ab + k2, K, rbA1, Acur + 8192, w, l);
    stage_unit(Bb + k2, K, rbB0, Bcur, w, l);
    wg_barrier();
    __builtin_amdgcn_s_setprio(1);
#pragma unroll
    for (int ks = 0; ks < 4; ks++) {
      acc[0][1] = __builtin_amdgcn_mfma_f32_32x32x16_bf16(aL0[ks], bG[ks], acc[0][1], 0, 0, 0);
      acc[1][1] = __builtin_amdgcn_mfma_f32_32x32x16_bf16(aL1[ks], bG[ks], acc[1][1], 0, 0, 0);
      acc[2][1] = __builtin_amdgcn_mfma_f32_32x32x16_bf16(aH0[ks], bG[ks], acc[2][1], 0, 0, 0);
      acc[3][1] = __builtin_amdgcn_mfma_f32_32x32x16_bf16(aH1[ks], bG[ks], acc[3][1], 0, 0, 0);
    }
    __builtin_amdgcn_s_setprio(0);
    asm volatile("s_waitcnt vmcnt(8)" ::: "memory");
    wg_barrier();
  }

  // ---- epilogue: 32x32 C/D layout: col = lane&31, row = (r&3)+8*(r>>2)+4*(lane>>5)
  // global row = rowBase + wm*128 + mt*32 + lk*4 + (r&3) + 8*(r>>2)
  // global col = colBase + wn*64 + ntile*32 + l31
  if (EPI == 0) {
    short* C = (short*)Cp + (size_t)bz * Cbatch;
#pragma unroll
    for (int n = 0; n < 2; n++) {
      const int col = colBase + wn * 64 + n * 32 + l31;
      const float bb = bias[col];
#pragma unroll
      for (int m = 0; m < 4; m++)
#pragma unroll
        for (int r = 0; r < 16; r++) {
          const size_t row = (size_t)rowBase + wm * 128 + m * 32 + lk * 4 + (r & 3) + 8 * (r >> 2);
          C[row * (size_t)ldc + col] = f2bs(acc[m][n][r] + bb);
        }
    }
  } else if (EPI == 1) {
    short* C = (short*)Cp + (size_t)bz * Cbatch;
    bool mk[2];
    int cols[2];
#pragma unroll
    for (int n = 0; n < 2; n++) {
      cols[n] = colBase + wn * 64 + n * 32 + l31;
      mk[n] = mask[(size_t)bz * 2048 + cols[n]] != 0;
    }
#pragma unroll
    for (int m = 0; m < 4; m++)
#pragma unroll
      for (int r = 0; r < 16; r++) {
        const int rowl = rowBase + wm * 128 + m * 32 + lk * 4 + (r & 3) + 8 * (r >> 2);
        float s = 0.f;
#pragma unroll
        for (int n = 0; n < 2; n++) {
          const float e = mk[n] ? __expf(fminf(acc[m][n][r] * scale, 30.f)) : 0.f;
          const short eb = f2bs(e);
          C[(size_t)rowl * (size_t)ldc + cols[n]] = eb;
          s += b2f(eb);
        }
        s += __shfl_xor(s, 1, 64);
        s += __shfl_xor(s, 2, 64);
        s += __shfl_xor(s, 4, 64);
        s += __shfl_xor(s, 8, 64);
        s += __shfl_xor(s, 16, 64);
        if (l31 == 0)
          partial[((size_t)bz * 1024 + rowl) * 8 + bx] = s;
      }
  } else if (EPI == 3) {
    short* C = (short*)Cp + (size_t)bz * Cbatch;
#pragma unroll
    for (int m = 0; m < 4; m++)
#pragma unroll
      for (int r2 = 0; r2 < 4; r2++) {
        const int rbase = rowBase + wm * 128 + m * 32 + lk * 4 + 8 * r2;
        f32x4 b4 = *(const f32x4*)&bias[rbase];
#pragma unroll
        for (int n = 0; n < 2; n++) {
          const int col = colBase + wn * 64 + n * 32 + l31;
#pragma unroll
          for (int i = 0; i < 4; i++) {
            const size_t row = (size_t)rbase + i;
            C[row * (size_t)ldc + col] = f2bs(acc[m][n][r2 * 4 + i] + b4[i]);
          }
        }
      }
  } else {
    // EPI 5: PV, multiply by rsinv[row], bf16 out
    short* C = (short*)Cp + (size_t)bz * Cbatch;
#pragma unroll
    for (int m = 0; m < 4; m++)
#pragma unroll
      for (int r2 = 0; r2 < 4; r2++) {
        const int rbase = rowBase + wm * 128 + m * 32 + lk * 4 + 8 * r2;
        f32x4 rv = *(const f32x4*)&rsinv[(size_t)bz * 1024 + rbase];
#pragma unroll
        for (int n = 0; n < 2; n++) {
          const int col = colBase + wn * 64 + n * 32 + l31;
#pragma unroll
          for (int i = 0; i < 4; i++) {
            const size_t row = (size_t)rbase + i;
            C[row * (size_t)ldc + col] = f2bs(acc[m][n][r2 * 4 + i] * rv[i]);
          }
        }
      }
  }
}

// ---------------- row-sum reduce: rsinv = 1 / sum(partial[row][0..8)) ------
__global__ __launch_bounds__(256) void rsum_kernel(const float* __restrict__ partial,
                                                   float* __restrict__ rsinv) {
  const size_t r = (size_t)blockIdx.x * 256 + threadIdx.x;
  f32x4 a = *(const f32x4*)(partial + r * 8);
  f32x4 b = *(const f32x4*)(partial + r * 8 + 4);
  float s = (a[0] + a[1]) + (a[2] + a[3]) + (b[0] + b[1]) + (b[2] + b[3]);
  rsinv[r] = 1.f / fmaxf(s, 1e-30f);
}

// -------- final LayerNorm: bf16 in (cross), fp32 out (d_out) ---------------
__global__ __launch_bounds__(256) void final_ln_kernel(const short* __restrict__ X,
                                                       const float* __restrict__ g,
                                                       const float* __restrict__ b,
                                                       float* __restrict__ Y) {
  const size_t row = (size_t)blockIdx.x * 4 + (threadIdx.x >> 6);
  const int lane = threadIdx.x & 63;
  const short* r = X + row * 1024;
  float f[16];
  float s = 0.f, ss = 0.f;
#pragma unroll
  for (int j = 0; j < 2; j++) {
    short8 v = *(const short8*)(r + j * 512 + lane * 8);
#pragma unroll
    for (int i = 0; i < 8; i++) {
      float x = b2f(v[i]);
      f[j * 8 + i] = x;
      s += x;
      ss += x * x;
    }
  }
  for (int o = 32; o > 0; o >>= 1) { s += __shfl_xor(s, o, 64); ss += __shfl_xor(ss, o, 64); }
  const float m = s * (1.f / 1024.f);
  const float rstd = rsqrtf(ss * (1.f / 1024.f) - m * m + 1e-5f);
#pragma unroll
  for (int j = 0; j < 2; j++) {
#pragma unroll
    for (int q = 0; q < 2; q++) {
      const int off = j * 512 + lane * 8 + q * 4;
      f32x4 gg = *(const f32x4*)(g + off);
      f32x4 bb = *(const f32x4*)(b + off);
      f32x4 y;
#pragma unroll
      for (int c = 0; c < 4; c++) y[c] = (f[j * 8 + q * 4 + c] - m) * rstd * gg[c] + bb[c];
      *(f32x4*)(Y + row * 1024 + off) = y;
    }
  }
}

extern "C" void kernel_launch(void* const* d_in, const int* in_sizes, int n_in,
                              void* d_out, int out_size, void* d_ws, size_t ws_size,
                              hipStream_t stream) {
  const float* text = (const float*)d_in[0];
  const float* audio = (const float*)d_in[1];
  const int* amask = (const int*)d_in[2];
  const float* ln_t_g = (const float*)d_in[3];
  const float* ln_t_b = (const float*)d_in[4];
  const float* ln_a_g = (const float*)d_in[5];
  const float* ln_a_b = (const float*)d_in[6];
  const float* Wq = (const float*)d_in[7];
  const float* bq = (const float*)d_in[8];
  const float* Wk = (const float*)d_in[9];
  const float* bk = (const float*)d_in[10];
  const float* Wv = (const float*)d_in[11];
  const float* bv = (const float*)d_in[12];
  const float* ln_p_g = (const float*)d_in[13];
  const float* ln_p_b = (const float*)d_in[14];

  char* p = (char*)d_ws;
  short* tb = (short*)p;  p += (size_t)32768 * 1024 * 2;   // 64 MB  (LN text, bf16)
  short* ab = (short*)p;  p += (size_t)65536 * 1024 * 2;   // 128 MB (LN audio, bf16)
  short* Wqt = (short*)p; p += (size_t)1024 * 1024 * 2;
  short* Wkt = (short*)p; p += (size_t)1024 * 1024 * 2;
  short* Wvt = (short*)p; p += (size_t)1024 * 1024 * 2;
  short* qb = (short*)p;  p += (size_t)32768 * 1024 * 2;   // 64 MB
  short* kb = (short*)p;  p += (size_t)65536 * 1024 * 2;   // 128 MB
  short* vTb = (short*)p; p += (size_t)32 * 1024 * 2048 * 2;  // 128 MB, [b][d][s]
  float* partial = (float*)p; p += (size_t)32768 * 8 * 4;     // 1 MB
  float* rsinv = (float*)p;   p += (size_t)32768 * 4;         // 128 KB
  // P aliases tb+ab (dead once qb/kb/vTb are built); cross (bf16) aliases qb
  short* Pb = tb;
  short* crossb = qb;
  (void)ws_size; (void)in_sizes; (void)n_in; (void)out_size;

  // 1. LN -> bf16 (text + audio, one launch)
  ln2_kernel<<<24576, 256, 0, stream>>>(text, audio, ln_t_g, ln_t_b, ln_a_g, ln_a_b, tb, ab);
  // 2. weight transpose+convert (one launch)
  wtrans3_kernel<<<dim3(32, 32, 3), 256, 0, stream>>>(Wq, Wk, Wv, Wqt, Wkt, Wvt);
  // 3. q = tb @ Wqt^T + bq   [32768 x 1024]
  gemm8_kernel<0><<<dim3(4, 128, 1), 512, 0, stream>>>(
      tb, Wqt, qb, 1024, 1024, 0, 0, 0, bq, nullptr, 0.f, nullptr, nullptr);
  // 4. k = ab @ Wkt^T + bk   [65536 x 1024]
  gemm8_kernel<0><<<dim3(4, 256, 1), 512, 0, stream>>>(
      ab, Wkt, kb, 1024, 1024, 0, 0, 0, bk, nullptr, 0.f, nullptr, nullptr);
  // 5. vT[b][d][s] = (ab @ Wvt^T + bv)^T : A=Wvt (M=1024 d), B=ab[b] (N=2048 s)
  gemm8_kernel<3><<<dim3(8, 4, 32), 512, 0, stream>>>(
      Wvt, ab, vTb, 1024, 2048, 0, (long)2048 * 1024, (long)1024 * 2048,
      bv, nullptr, 0.f, nullptr, nullptr);
  // 6. P = exp(scale * q@k^T) masked -> bf16 [32][1024][2048] + row partials
  gemm8_kernel<1><<<dim3(8, 4, 32), 512, 0, stream>>>(
      qb, kb, Pb, 1024, 2048, (long)1024 * 1024, (long)2048 * 1024,
      (long)1024 * 2048, nullptr, amask, 0.03125f, partial, nullptr);
  // 7. rsinv[row] = 1 / sum_j partial[row][j]
  rsum_kernel<<<128, 256, 0, stream>>>(partial, rsinv);
  // 8. cross = (P @ vT^T) * rsinv -> bf16 [32][1024][1024] (into crossb = qb)
  gemm8_kernel<5><<<dim3(4, 4, 32), 512, 0, stream>>>(
      Pb, vTb, crossb, 2048, 1024, (long)1024 * 2048, (long)1024 * 2048,
      (long)1024 * 1024, nullptr, nullptr, 0.f, nullptr, rsinv);
  // 9. final LayerNorm: crossb (bf16) -> d_out (fp32)
  final_ln_kernel<<<8192, 256, 0, stream>>>(crossb, ln_p_g, ln_p_b, (float*)d_out);
}

// Round 6
// 861.263 us; speedup vs baseline: 1.1116x; 1.1116x over previous
//
#include <hip/hip_runtime.h>

typedef __attribute__((ext_vector_type(8))) short short8;
typedef __attribute__((ext_vector_type(4))) short short4_t;
typedef __attribute__((ext_vector_type(4))) float f32x4;

#define DEVI static __device__ __forceinline__

DEVI float b2f(short s) { return __uint_as_float(((unsigned)(unsigned short)s) << 16); }
DEVI short f2bs(float x) {
  unsigned u = __float_as_uint(x);
  unsigned r = (u + 0x7FFFu + ((u >> 16) & 1u)) >> 16;
  return (short)(unsigned short)r;
}

DEVI void gload16(const short* g, short* l) {
  __builtin_amdgcn_global_load_lds(
      (const __attribute__((address_space(1))) void*)g,
      (__attribute__((address_space(3))) void*)l, 16, 0, 0);
}

DEVI void wg_barrier() {
  asm volatile("" ::: "memory");
  __builtin_amdgcn_s_barrier();
  asm volatile("" ::: "memory");
}

// Stage one 128x64 bf16 unit: 8 waves x 2 gloads x 64 lanes x 16B = 16KB.
// LDS dest linear (wave-uniform + lane*16); global source pre-swizzled:
// lane row = rowbase_w + i*8 + (l>>3); source slot = (l&7) ^ (l>>3).
// Resulting LDS: unit[row][64] with slot c holding k-chunk (c ^ (row&7)).
DEVI void stage_unit(const short* __restrict__ gTile, int K, int rowbase_w,
                     short* lUnit, int w, int l) {
  const int rr = l >> 3;
  const int slot = ((l & 7) ^ rr) << 3;
  const short* g0 = gTile + (size_t)(rowbase_w + rr) * K + slot;
  gload16(g0, lUnit + w * 1024);
  gload16(g0 + (size_t)8 * K, lUnit + w * 1024 + 512);
}

// ---------- fused LayerNorm -> bf16 for text AND audio (one launch) --------
__global__ __launch_bounds__(256) void ln2_kernel(
    const float* __restrict__ text, const float* __restrict__ audio,
    const float* __restrict__ gt, const float* __restrict__ bt,
    const float* __restrict__ ga, const float* __restrict__ ba,
    short* __restrict__ tb, short* __restrict__ ab) {
  const size_t row = (size_t)blockIdx.x * 4 + (threadIdx.x >> 6);
  const int lane = threadIdx.x & 63;
  const bool isT = row < 32768;
  const float* X = isT ? text + row * 1024 : audio + (row - 32768) * 1024;
  const float* g = isT ? gt : ga;
  const float* b = isT ? bt : ba;
  short* Y = isT ? tb + row * 1024 : ab + (row - 32768) * 1024;
  f32x4 x[4];
  float s = 0.f, ss = 0.f;
#pragma unroll
  for (int j = 0; j < 4; j++) {
    x[j] = *(const f32x4*)(X + j * 256 + lane * 4);
#pragma unroll
    for (int c = 0; c < 4; c++) { s += x[j][c]; ss += x[j][c] * x[j][c]; }
  }
  for (int o = 32; o > 0; o >>= 1) { s += __shfl_xor(s, o, 64); ss += __shfl_xor(ss, o, 64); }
  const float m = s * (1.f / 1024.f);
  const float rstd = rsqrtf(ss * (1.f / 1024.f) - m * m + 1e-5f);
#pragma unroll
  for (int j = 0; j < 4; j++) {
    f32x4 gg = *(const f32x4*)(g + j * 256 + lane * 4);
    f32x4 bb = *(const f32x4*)(b + j * 256 + lane * 4);
    short4_t o4;
#pragma unroll
    for (int c = 0; c < 4; c++) o4[c] = f2bs((x[j][c] - m) * rstd * gg[c] + bb[c]);
    *(short4_t*)(Y + j * 256 + lane * 4) = o4;
  }
}

// ------------ W [K][N] fp32 -> Wt [N][K] bf16, all three weights -----------
__global__ __launch_bounds__(256) void wtrans3_kernel(
    const float* __restrict__ W0, const float* __restrict__ W1,
    const float* __restrict__ W2, short* __restrict__ T0,
    short* __restrict__ T1, short* __restrict__ T2) {
  const float* W = blockIdx.z == 0 ? W0 : (blockIdx.z == 1 ? W1 : W2);
  short* Wt = blockIdx.z == 0 ? T0 : (blockIdx.z == 1 ? T1 : T2);
  __shared__ float tile[32][33];
  const int tx = threadIdx.x & 31;
  const int ty = threadIdx.x >> 5;  // 0..7
  const int c0 = blockIdx.x * 32, r0 = blockIdx.y * 32;
#pragma unroll
  for (int rr = 0; rr < 4; rr++)
    tile[ty + rr * 8][tx] = W[(size_t)(r0 + ty + rr * 8) * 1024 + c0 + tx];
  __syncthreads();
#pragma unroll
  for (int rr = 0; rr < 4; rr++)
    Wt[(size_t)(c0 + ty + rr * 8) * 1024 + r0 + tx] = f2bs(tile[tx][ty + rr * 8]);
}

// ============ 256x256 4-phase MFMA GEMM, 16x16x32 core (r3-proven) =========
// A bf16 [M][K] K-contig, B bf16 [N][K] K-contig, BK=64, 8 waves (2Mx4N),
// per-wave out 128x64. LDS 128KB: A[2buf][2reg][128][64] + B same.
// Single vmcnt(6) per K-tile at P3-end (m201-style counted wait): covers all
// of tile t+1's consumption; the 6 outstanding are t.P1/P2/P3's loads.
// EPI 0: +bias[col] bf16 | 1: exp(s*scale) masked + row partials | 3: +bias[row]
// EPI 5: *rsinv[row] bf16
template <int EPI>
__global__ __launch_bounds__(512, 2) void gemm8_kernel(
    const short* __restrict__ A, const short* __restrict__ B, void* __restrict__ Cp,
    int K, int ldc, long Abatch, long Bbatch, long Cbatch,
    const float* __restrict__ bias, const int* __restrict__ mask, float scale,
    float* __restrict__ partial, const float* __restrict__ rsinv) {
  __shared__ short lds[65536];
  const int t = threadIdx.x;
  const int w = t >> 6, l = t & 63;
  const int wm = w >> 2, wn = w & 3;
  const int fr = l & 15, fg = l >> 4, fr7 = l & 7;

  // XCD-chunked block swizzle (nwg % 8 == 0 by construction)
  const int gx = gridDim.x, gy = gridDim.y;
  const int nwg = gx * gy * (int)gridDim.z;
  int lin = blockIdx.x + gx * (blockIdx.y + gy * blockIdx.z);
  lin = (lin & 7) * (nwg >> 3) + (lin >> 3);
  const int bx = lin % gx;
  const int by = (lin / gx) % gy;
  const int bz = lin / (gx * gy);

  const int rowBase = by * 256;
  const int colBase = bx * 256;
  const short* Ab = A + (size_t)bz * Abatch + (size_t)rowBase * K;
  const short* Bb = B + (size_t)bz * Bbatch + (size_t)colBase * K;

  short* As = lds;            // [buf][reg][128][64]
  short* Bs = lds + 32768;

  f32x4 acc[8][4];
#pragma unroll
  for (int m = 0; m < 8; m++)
#pragma unroll
    for (int n = 0; n < 4; n++) acc[m][n] = (f32x4){0.f, 0.f, 0.f, 0.f};

  const int nt = K >> 6;
  const int ntm1 = nt - 1;

  // stage row bases (per wave)
  const int rbA0 = (w >> 2) * 128 + (w & 3) * 16;  // A region 0
  const int rbA1 = rbA0 + 64;                      // A region 1
  const int rbB0 = (w >> 1) * 64 + (w & 1) * 16;   // B region 0
  const int rbB1 = rbB0 + 32;                      // B region 1

  // ---- prologue: 7 units (tile0 all 4, tile1 first 3)
  stage_unit(Ab, K, rbA0, As, w, l);
  stage_unit(Bb, K, rbB0, Bs, w, l);
  stage_unit(Ab, K, rbA1, As + 8192, w, l);
  stage_unit(Bb, K, rbB1, Bs + 8192, w, l);
  {
    const int kp = (nt > 1) ? 64 : 0;
    stage_unit(Ab + kp, K, rbA0, As + 16384, w, l);
    stage_unit(Bb + kp, K, rbB0, Bs + 16384, w, l);
    stage_unit(Ab + kp, K, rbA1, As + 24576, w, l);
  }
  asm volatile("s_waitcnt vmcnt(6)" ::: "memory");
  wg_barrier();

  // fragment read offsets (elements)
  const int rowA = (wm * 64 + fr) * 64;  // + m*1024 + reg*8192
  const int rowB = (wn * 32 + fr) * 64;  // + n*1024 + reg*8192
  const int ks0 = (fg ^ fr7) << 3;
  const int ks1 = ((4 + fg) ^ fr7) << 3;

  short8 aL[4][2], aH[4][2], bF[2][2];

  for (int tt = 0; tt < nt; ++tt) {
    const int c = tt & 1;
    const short* Ac = As + c * 16384;
    const short* Bc = Bs + c * 16384;
    short* Acur = As + c * 16384;
    short* Bcur = Bs + c * 16384;
    short* Bnx = Bs + (c ^ 1) * 16384;
    const int k1 = ((tt + 1 <= ntm1) ? tt + 1 : ntm1) * 64;
    const int k2 = ((tt + 2 <= ntm1) ? tt + 2 : ntm1) * 64;

    // ---- P0: quadrant (mh0,nh0); 12 ds_reads; stage B-r1(t+1)
#pragma unroll
    for (int m = 0; m < 4; m++) {
      aL[m][0] = *(const short8*)&Ac[rowA + m * 1024 + ks0];
      aL[m][1] = *(const short8*)&Ac[rowA + m * 1024 + ks1];
    }
#pragma unroll
    for (int n = 0; n < 2; n++) {
      bF[n][0] = *(const short8*)&Bc[rowB + n * 1024 + ks0];
      bF[n][1] = *(const short8*)&Bc[rowB + n * 1024 + ks1];
    }
    stage_unit(Bb + k1, K, rbB1, Bnx + 8192, w, l);
    wg_barrier();
    __builtin_amdgcn_s_setprio(1);
#pragma unroll
    for (int m = 0; m < 4; m++)
#pragma unroll
      for (int n = 0; n < 2; n++) {
        acc[m][n] = __builtin_amdgcn_mfma_f32_16x16x32_bf16(aL[m][0], bF[n][0], acc[m][n], 0, 0, 0);
        acc[m][n] = __builtin_amdgcn_mfma_f32_16x16x32_bf16(aL[m][1], bF[n][1], acc[m][n], 0, 0, 0);
      }
    __builtin_amdgcn_s_setprio(0);
    wg_barrier();

    // ---- P1: quadrant (mh1,nh0); 8 ds_reads; stage A-r0(t+2)
#pragma unroll
    for (int m = 0; m < 4; m++) {
      aH[m][0] = *(const short8*)&Ac[8192 + rowA + m * 1024 + ks0];
      aH[m][1] = *(const short8*)&Ac[8192 + rowA + m * 1024 + ks1];
    }
    stage_unit(Ab + k2, K, rbA0, Acur, w, l);
    wg_barrier();
    __builtin_amdgcn_s_setprio(1);
#pragma unroll
    for (int m = 0; m < 4; m++)
#pragma unroll
      for (int n = 0; n < 2; n++) {
        acc[4 + m][n] = __builtin_amdgcn_mfma_f32_16x16x32_bf16(aH[m][0], bF[n][0], acc[4 + m][n], 0, 0, 0);
        acc[4 + m][n] = __builtin_amdgcn_mfma_f32_16x16x32_bf16(aH[m][1], bF[n][1], acc[4 + m][n], 0, 0, 0);
      }
    __builtin_amdgcn_s_setprio(0);
    wg_barrier();

    // ---- P2: quadrant (mh0,nh1); 4 ds_reads; stage B-r0(t+2)
#pragma unroll
    for (int n = 0; n < 2; n++) {
      bF[n][0] = *(const short8*)&Bc[8192 + rowB + n * 1024 + ks0];
      bF[n][1] = *(const short8*)&Bc[8192 + rowB + n * 1024 + ks1];
    }
    stage_unit(Bb + k2, K, rbB0, Bcur, w, l);
    wg_barrier();
    __builtin_amdgcn_s_setprio(1);
#pragma unroll
    for (int m = 0; m < 4; m++)
#pragma unroll
      for (int n = 0; n < 2; n++) {
        acc[m][2 + n] = __builtin_amdgcn_mfma_f32_16x16x32_bf16(aL[m][0], bF[n][0], acc[m][2 + n], 0, 0, 0);
        acc[m][2 + n] = __builtin_amdgcn_mfma_f32_16x16x32_bf16(aL[m][1], bF[n][1], acc[m][2 + n], 0, 0, 0);
      }
    __builtin_amdgcn_s_setprio(0);
    wg_barrier();

    // ---- P3: quadrant (mh1,nh1); 0 ds_reads; stage A-r1(t+2)
    stage_unit(Ab + k2, K, rbA1, Acur + 8192, w, l);
    wg_barrier();
    __builtin_amdgcn_s_setprio(1);
#pragma unroll
    for (int m = 0; m < 4; m++)
#pragma unroll
      for (int n = 0; n < 2; n++) {
        acc[4 + m][2 + n] = __builtin_amdgcn_mfma_f32_16x16x32_bf16(aH[m][0], bF[n][0], acc[4 + m][2 + n], 0, 0, 0);
        acc[4 + m][2 + n] = __builtin_amdgcn_mfma_f32_16x16x32_bf16(aH[m][1], bF[n][1], acc[4 + m][2 + n], 0, 0, 0);
      }
    __builtin_amdgcn_s_setprio(0);
    asm volatile("s_waitcnt vmcnt(6)" ::: "memory");
    wg_barrier();
  }

  // ---- epilogue: rows rowBase + wm*128 + mi*16 + fg*4 + j, cols colBase + wn*64 + ni*16 + fr
  if (EPI == 0) {
    short* C = (short*)Cp + (size_t)bz * Cbatch;
#pragma unroll
    for (int ni = 0; ni < 4; ni++) {
      const int col = colBase + wn * 64 + ni * 16 + fr;
      const float bb = bias[col];
#pragma unroll
      for (int mi = 0; mi < 8; mi++)
#pragma unroll
        for (int j = 0; j < 4; j++) {
          const size_t row = (size_t)rowBase + wm * 128 + mi * 16 + fg * 4 + j;
          C[row * (size_t)ldc + col] = f2bs(acc[mi][ni][j] + bb);
        }
    }
  } else if (EPI == 1) {
    short* C = (short*)Cp + (size_t)bz * Cbatch;
    bool mk[4];
    int cols[4];
#pragma unroll
    for (int ni = 0; ni < 4; ni++) {
      cols[ni] = colBase + wn * 64 + ni * 16 + fr;
      mk[ni] = mask[(size_t)bz * 2048 + cols[ni]] != 0;
    }
#pragma unroll
    for (int mi = 0; mi < 8; mi++)
#pragma unroll
      for (int j = 0; j < 4; j++) {
        const int rowl = rowBase + wm * 128 + mi * 16 + fg * 4 + j;
        float s = 0.f;
#pragma unroll
        for (int ni = 0; ni < 4; ni++) {
          const float e = mk[ni] ? __expf(fminf(acc[mi][ni][j] * scale, 30.f)) : 0.f;
          const short eb = f2bs(e);
          C[(size_t)rowl * (size_t)ldc + cols[ni]] = eb;
          s += b2f(eb);
        }
        s += __shfl_xor(s, 1, 64);
        s += __shfl_xor(s, 2, 64);
        s += __shfl_xor(s, 4, 64);
        s += __shfl_xor(s, 8, 64);
        if ((l & 15) == 0)
          partial[((size_t)bz * 1024 + rowl) * 32 + bx * 4 + wn] = s;
      }
  } else if (EPI == 3) {
    short* C = (short*)Cp + (size_t)bz * Cbatch;
#pragma unroll
    for (int mi = 0; mi < 8; mi++) {
      f32x4 b4 = *(const f32x4*)&bias[rowBase + wm * 128 + mi * 16 + fg * 4];
#pragma unroll
      for (int ni = 0; ni < 4; ni++) {
        const int col = colBase + wn * 64 + ni * 16 + fr;
#pragma unroll
        for (int j = 0; j < 4; j++) {
          const size_t row = (size_t)rowBase + wm * 128 + mi * 16 + fg * 4 + j;
          C[row * (size_t)ldc + col] = f2bs(acc[mi][ni][j] + b4[j]);
        }
      }
    }
  } else {
    // EPI 5: PV, multiply by rsinv[row], bf16 out
    short* C = (short*)Cp + (size_t)bz * Cbatch;
#pragma unroll
    for (int mi = 0; mi < 8; mi++) {
      const int rbase = rowBase + wm * 128 + mi * 16 + fg * 4;
      f32x4 rv = *(const f32x4*)&rsinv[(size_t)bz * 1024 + rbase];
#pragma unroll
      for (int ni = 0; ni < 4; ni++) {
        const int col = colBase + wn * 64 + ni * 16 + fr;
#pragma unroll
        for (int j = 0; j < 4; j++)
          C[((size_t)rbase + j) * (size_t)ldc + col] = f2bs(acc[mi][ni][j] * rv[j]);
      }
    }
  }
}

// ---------------- row-sum reduce: rsinv = 1 / sum(partial[row][0..32)) -----
__global__ __launch_bounds__(256) void rsum_kernel(const float* __restrict__ partial,
                                                   float* __restrict__ rsinv) {
  const size_t r = (size_t)blockIdx.x * 256 + threadIdx.x;
  float s = 0.f;
#pragma unroll
  for (int j = 0; j < 8; j++) {
    f32x4 a = *(const f32x4*)(partial + r * 32 + j * 4);
    s += (a[0] + a[1]) + (a[2] + a[3]);
  }
  rsinv[r] = 1.f / fmaxf(s, 1e-30f);
}

// -------- final LayerNorm: bf16 in (cross), fp32 out (d_out) ---------------
__global__ __launch_bounds__(256) void final_ln_kernel(const short* __restrict__ X,
                                                       const float* __restrict__ g,
                                                       const float* __restrict__ b,
                                                       float* __restrict__ Y) {
  const size_t row = (size_t)blockIdx.x * 4 + (threadIdx.x >> 6);
  const int lane = threadIdx.x & 63;
  const short* r = X + row * 1024;
  float f[16];
  float s = 0.f, ss = 0.f;
#pragma unroll
  for (int j = 0; j < 2; j++) {
    short8 v = *(const short8*)(r + j * 512 + lane * 8);
#pragma unroll
    for (int i = 0; i < 8; i++) {
      float x = b2f(v[i]);
      f[j * 8 + i] = x;
      s += x;
      ss += x * x;
    }
  }
  for (int o = 32; o > 0; o >>= 1) { s += __shfl_xor(s, o, 64); ss += __shfl_xor(ss, o, 64); }
  const float m = s * (1.f / 1024.f);
  const float rstd = rsqrtf(ss * (1.f / 1024.f) - m * m + 1e-5f);
#pragma unroll
  for (int j = 0; j < 2; j++) {
#pragma unroll
    for (int q = 0; q < 2; q++) {
      const int off = j * 512 + lane * 8 + q * 4;
      f32x4 gg = *(const f32x4*)(g + off);
      f32x4 bb = *(const f32x4*)(b + off);
      f32x4 y;
#pragma unroll
      for (int c = 0; c < 4; c++) y[c] = (f[j * 8 + q * 4 + c] - m) * rstd * gg[c] + bb[c];
      *(f32x4*)(Y + row * 1024 + off) = y;
    }
  }
}

extern "C" void kernel_launch(void* const* d_in, const int* in_sizes, int n_in,
                              void* d_out, int out_size, void* d_ws, size_t ws_size,
                              hipStream_t stream) {
  const float* text = (const float*)d_in[0];
  const float* audio = (const float*)d_in[1];
  const int* amask = (const int*)d_in[2];
  const float* ln_t_g = (const float*)d_in[3];
  const float* ln_t_b = (const float*)d_in[4];
  const float* ln_a_g = (const float*)d_in[5];
  const float* ln_a_b = (const float*)d_in[6];
  const float* Wq = (const float*)d_in[7];
  const float* bq = (const float*)d_in[8];
  const float* Wk = (const float*)d_in[9];
  const float* bk = (const float*)d_in[10];
  const float* Wv = (const float*)d_in[11];
  const float* bv = (const float*)d_in[12];
  const float* ln_p_g = (const float*)d_in[13];
  const float* ln_p_b = (const float*)d_in[14];

  char* p = (char*)d_ws;
  short* tb = (short*)p;  p += (size_t)32768 * 1024 * 2;   // 64 MB  (LN text, bf16)
  short* ab = (short*)p;  p += (size_t)65536 * 1024 * 2;   // 128 MB (LN audio, bf16)
  short* Wqt = (short*)p; p += (size_t)1024 * 1024 * 2;
  short* Wkt = (short*)p; p += (size_t)1024 * 1024 * 2;
  short* Wvt = (short*)p; p += (size_t)1024 * 1024 * 2;
  short* qb = (short*)p;  p += (size_t)32768 * 1024 * 2;   // 64 MB
  short* kb = (short*)p;  p += (size_t)65536 * 1024 * 2;   // 128 MB
  short* vTb = (short*)p; p += (size_t)32 * 1024 * 2048 * 2;  // 128 MB, [b][d][s]
  float* partial = (float*)p; p += (size_t)32768 * 32 * 4;    // 4 MB
  float* rsinv = (float*)p;   p += (size_t)32768 * 4;         // 128 KB
  // P aliases tb+ab (dead once qb/kb/vTb are built); cross (bf16) aliases qb
  short* Pb = tb;
  short* crossb = qb;
  (void)ws_size; (void)in_sizes; (void)n_in; (void)out_size;

  // 1. LN -> bf16 (text + audio, one launch)
  ln2_kernel<<<24576, 256, 0, stream>>>(text, audio, ln_t_g, ln_t_b, ln_a_g, ln_a_b, tb, ab);
  // 2. weight transpose+convert (one launch)
  wtrans3_kernel<<<dim3(32, 32, 3), 256, 0, stream>>>(Wq, Wk, Wv, Wqt, Wkt, Wvt);
  // 3. q = tb @ Wqt^T + bq   [32768 x 1024]
  gemm8_kernel<0><<<dim3(4, 128, 1), 512, 0, stream>>>(
      tb, Wqt, qb, 1024, 1024, 0, 0, 0, bq, nullptr, 0.f, nullptr, nullptr);
  // 4. k = ab @ Wkt^T + bk   [65536 x 1024]
  gemm8_kernel<0><<<dim3(4, 256, 1), 512, 0, stream>>>(
      ab, Wkt, kb, 1024, 1024, 0, 0, 0, bk, nullptr, 0.f, nullptr, nullptr);
  // 5. vT[b][d][s] = (ab @ Wvt^T + bv)^T : A=Wvt (M=1024 d), B=ab[b] (N=2048 s)
  gemm8_kernel<3><<<dim3(8, 4, 32), 512, 0, stream>>>(
      Wvt, ab, vTb, 1024, 2048, 0, (long)2048 * 1024, (long)1024 * 2048,
      bv, nullptr, 0.f, nullptr, nullptr);
  // 6. P = exp(scale * q@k^T) masked -> bf16 [32][1024][2048] + row partials
  gemm8_kernel<1><<<dim3(8, 4, 32), 512, 0, stream>>>(
      qb, kb, Pb, 1024, 2048, (long)1024 * 1024, (long)2048 * 1024,
      (long)1024 * 2048, nullptr, amask, 0.03125f, partial, nullptr);
  // 7. rsinv[row] = 1 / sum_j partial[row][j]
  rsum_kernel<<<128, 256, 0, stream>>>(partial, rsinv);
  // 8. cross = (P @ vT^T) * rsinv -> bf16 [32][1024][1024] (into crossb = qb)
  gemm8_kernel<5><<<dim3(4, 4, 32), 512, 0, stream>>>(
      Pb, vTb, crossb, 2048, 1024, (long)1024 * 2048, (long)1024 * 2048,
      (long)1024 * 1024, nullptr, nullptr, 0.f, nullptr, rsinv);
  // 9. final LayerNorm: crossb (bf16) -> d_out (fp32)
  final_ln_kernel<<<8192, 256, 0, stream>>>(crossb, ln_p_g, ln_p_b, (float*)d_out);
}